// Round 11
// baseline (308.014 us; speedup 1.0000x reference)
//
#include <hip/hip_runtime.h>
#include <stdint.h>

// Problem dims (fixed by the reference)
constexpr int B_ = 2, S_ = 2048, E_ = 1024, H_ = 16, D_ = 64;
constexpr int M_ = B_ * S_;              // 4096 rows

typedef unsigned short u16;
typedef __attribute__((ext_vector_type(8))) short short8;
typedef __attribute__((ext_vector_type(4))) float f32x4;

__device__ __forceinline__ u16 f2bf(float f) {
  uint32_t u = __float_as_uint(f);
  return (u16)((u + 0x7FFFu + ((u >> 16) & 1u)) >> 16);  // RNE
}
// truncation split: hi = trunc16(x), lo = trunc16(x - hi). hi+lo ~ x to 2^-17.
__device__ __forceinline__ void tsplit(float x, u16& hi, u16& lo) {
  const uint32_t u = __float_as_uint(x);
  hi = (u16)(u >> 16);
  const float hif = __uint_as_float(u & 0xFFFF0000u);
  lo = (u16)(__float_as_uint(x - hif) >> 16);
}

// async global->LDS, 16 B per lane; LDS dest = wave-uniform base + lane*16.
typedef const __attribute__((address_space(1))) unsigned int GU32;
typedef __attribute__((address_space(3))) unsigned int LU32;
__device__ __forceinline__ void gload16(const void* g, void* l) {
  __builtin_amdgcn_global_load_lds((GU32*)g, (LU32*)l, 16, 0, 0);
}

// ---------------------------------------------------------------------------
// Kernel 0: split fp32 -> (hi, lo) bf16 pair, elementwise (weights).
// ---------------------------------------------------------------------------
__global__ __launch_bounds__(256) void split_f32_kernel(
    const float* __restrict__ src, u16* __restrict__ hi, u16* __restrict__ lo, int n4)
{
  const int i = blockIdx.x * 256 + threadIdx.x;
  if (i >= n4) return;
  const float4 x = ((const float4*)src)[i];
  ushort4 h, l;
  tsplit(x.x, h.x, l.x); tsplit(x.y, h.y, l.y);
  tsplit(x.z, h.z, l.z); tsplit(x.w, h.w, l.w);
  ((ushort4*)hi)[i] = h;
  ((ushort4*)lo)[i] = l;
}

// ---------------------------------------------------------------------------
// Kernel 0b: per-batch scan of key mask -> opos (compact slot j -> orig row s)
// and nk[b] (# unmasked keys).
// ---------------------------------------------------------------------------
__global__ __launch_bounds__(256) void mask_scan_kernel(
    const int* __restrict__ mask, int* __restrict__ opos, int* __restrict__ nk)
{
  __shared__ int tmp[256];
  __shared__ int coff;
  const int b = blockIdx.x, t = threadIdx.x;
  for (int c = t; c < S_; c += 256) opos[b * S_ + c] = 0;  // safe default
  if (t == 0) coff = 0;
  __syncthreads();
  for (int c = 0; c < S_; c += 256) {
    const int m = (mask[b * S_ + c + t] != 0) ? 1 : 0;
    int x = m;
    tmp[t] = x;
    __syncthreads();
#pragma unroll
    for (int off = 1; off < 256; off <<= 1) {
      const int v = (t >= off) ? tmp[t - off] : 0;
      __syncthreads();
      x += v;
      tmp[t] = x;
      __syncthreads();
    }
    const int base = coff;
    if (m) opos[b * S_ + base + x - 1] = c + t;  // scatter: slot -> orig row
    __syncthreads();
    if (t == 255) coff = base + x;
    __syncthreads();
  }
  if (t == 0) nk[b] = coff;
}

// ---------------------------------------------------------------------------
// Kernel 1: QKV projection, split-bf16 MFMA + key compaction.
// v11 = v10 + A staged via global_load_lds as RAW FP32 (linear [128][32],
// 16B-chunk XOR swizzle chunk^=(row&7), pre-swizzled source). tsplit moves
// to fragment-read (2x ds_read_b128 fp32 + 8 tsplits per mt). No VGPR
// round trip for either operand. LDS 36,864 B -> 4 blocks/CU.
// Tile 128x128, 4 waves (2m x 2n), wave = 64x64 (acc[4][4]).
// ---------------------------------------------------------------------------
__global__ __launch_bounds__(256) void gemm_qkv_kernel(
    const float* __restrict__ q, const float* __restrict__ k, const float* __restrict__ v,
    const u16* __restrict__ WHi, const u16* __restrict__ WLo,
    const float* __restrict__ bias,
    const int* __restrict__ Opos, const int* __restrict__ NkArr,
    u16* __restrict__ QpHi, u16* __restrict__ QpLo,
    u16* __restrict__ KpHi, u16* __restrict__ KpLo,
    u16* __restrict__ Vp)
{
  __shared__ __align__(16) short smem[18432];  // 36,864 B
  float* Af = (float*)smem;    // [128][32] fp32, swizzled chunks (16,384 B)
  short* Bh = smem + 8192;     // [128][32] bf16 hi, swizzled (8,192 B)
  short* Bl = smem + 12288;    // [128][32] bf16 lo, swizzled (8,192 B)

  const int t = threadIdx.x;
  const int m0 = blockIdx.x * 128;
  const int n0g = blockIdx.y * 128;          // global col in [0, 3072)
  const int proj = n0g >> 10;
  const int nloc = n0g & (E_ - 1);
  const bool split = (proj < 2);
  const int bb = m0 >> 11, mloc = m0 & (S_ - 1);
  const int nkb = NkArr[bb];
  if (proj != 0 && mloc >= nkb) return;      // compacted K/V: nothing to do

  const float* A = (proj == 0) ? q : (proj == 1) ? k : v;

  const int w = t >> 6, lane = t & 63;
  const int g = lane >> 4, lc = lane & 15;
  const int wm = w & 1, wn = w >> 1;

  // A gload geometry: thread stages physical chunks p_i = (i*4+w)*64+lane,
  // i=0..3. row = (i*4+w)*8 + (lane>>3); physical sub-chunk = lane&7;
  // source logical chunk = (lane&7) ^ (row&7) = (lane&7) ^ (lane>>3).
  const int lchA = (lane & 7) ^ (lane >> 3);
  const float* Asrc[4];
#pragma unroll
  for (int i = 0; i < 4; ++i) {
    const int r = (i * 4 + w) * 8 + (lane >> 3);
    int ga;
    if (proj == 0) ga = m0 + r;
    else ga = bb * S_ + (Opos[bb * S_ + mloc + r] & (S_ - 1));
    Asrc[i] = A + (size_t)ga * E_ + 4 * lchA;
  }
  // B: physical chunk p holds logical chunk (p&3)^((row>>1)&3) of row p>>2.
  auto gloadB = [&](int k0) {
#pragma unroll
    for (int i = 0; i < 2; ++i) {
      const int c = (w * 2 + i) * 64 + lane;
      const int row = c >> 2;
      const int sub = (c & 3) ^ ((row >> 1) & 3);
      const size_t go = (size_t)(n0g + row) * E_ + k0 + sub * 8;
      gload16(WHi + go, (char*)Bh + (w * 2 + i) * 1024);
      if (split) gload16(WLo + go, (char*)Bl + (w * 2 + i) * 1024);
    }
  };

  f32x4 acc[4][4];
#pragma unroll
  for (int i = 0; i < 4; ++i)
#pragma unroll
    for (int j = 0; j < 4; ++j) acc[i][j] = (f32x4){0.f, 0.f, 0.f, 0.f};

  for (int k0 = 0; k0 < E_; k0 += 32) {
    __syncthreads();                 // prev frag reads done -> LDS free
#pragma unroll
    for (int i = 0; i < 4; ++i)
      gload16(Asrc[i] + k0, (char*)Af + (i * 4 + w) * 1024);
    gloadB(k0);
    __syncthreads();                 // vmcnt drain: tiles arrived

    short8 ah[4], al[4], bh[4], bl[4];
#pragma unroll
    for (int mt = 0; mt < 4; ++mt) {
      const int R = wm * 64 + mt * 16 + lc;
      const int s = lc & 7;          // R&7 == lc&7
      const float4 f0 = *(const float4*)&Af[R * 32 + ((2 * g) ^ s) * 4];
      const float4 f1 = *(const float4*)&Af[R * 32 + ((2 * g + 1) ^ s) * 4];
      const float xs[8] = {f0.x, f0.y, f0.z, f0.w, f1.x, f1.y, f1.z, f1.w};
      ushort hh[8], ll[8];
#pragma unroll
      for (int j = 0; j < 8; ++j) tsplit(xs[j], hh[j], ll[j]);
      ah[mt] = *(const short8*)&hh[0];
      if (split) al[mt] = *(const short8*)&ll[0];
    }
#pragma unroll
    for (int nt = 0; nt < 4; ++nt) {
      const int row = wn * 64 + nt * 16 + lc;
      const int ro = row * 32 + ((g ^ ((row >> 1) & 3)) * 8);
      bh[nt] = *(const short8*)&Bh[ro];
      if (split) bl[nt] = *(const short8*)&Bl[ro];
    }
#pragma unroll
    for (int mt = 0; mt < 4; ++mt)
#pragma unroll
      for (int nt = 0; nt < 4; ++nt) {
        f32x4 a = acc[mt][nt];
        a = __builtin_amdgcn_mfma_f32_16x16x32_bf16(ah[mt], bh[nt], a, 0, 0, 0);
        if (split) {
          a = __builtin_amdgcn_mfma_f32_16x16x32_bf16(ah[mt], bl[nt], a, 0, 0, 0);
          a = __builtin_amdgcn_mfma_f32_16x16x32_bf16(al[mt], bh[nt], a, 0, 0, 0);
        }
        acc[mt][nt] = a;
      }
  }

  // ---- epilogue ----
  float bs[4];
#pragma unroll
  for (int nt = 0; nt < 4; ++nt) bs[nt] = bias[n0g + wn * 64 + nt * 16 + lc];

  if (proj < 2) {
    // each wave's 64 n-cols = exactly one head
    u16* Hi = (proj == 0) ? QpHi : KpHi;
    u16* Lo = (proj == 0) ? QpLo : KpLo;
    const int hwave = (nloc + wn * 64) >> 6;
    short* T = smem + w * 4608;               // per-wave [64][72] u16
    const int srow_out = (proj == 0) ? ((m0 + wm * 64 + lane) & (S_ - 1))
                                     : (mloc + wm * 64 + lane);
    const size_t rowb = (((size_t)(bb * H_ + hwave)) * S_ + srow_out) * D_;
#pragma unroll
    for (int pass = 0; pass < 2; ++pass) {
      __syncthreads();                        // LDS free / prev pass reads done
#pragma unroll
      for (int nt = 0; nt < 4; ++nt)
#pragma unroll
        for (int mt = 0; mt < 4; ++mt)
#pragma unroll
          for (int r = 0; r < 4; ++r) {
            const float val = acc[mt][nt][r] + bs[nt];
            const uint32_t u = __float_as_uint(val);
            u16 x;
            if (pass == 0) x = (u16)(u >> 16);
            else {
              const float hif = __uint_as_float(u & 0xFFFF0000u);
              x = (u16)(__float_as_uint(val - hif) >> 16);
            }
            T[(mt * 16 + g * 4 + r) * 72 + nt * 16 + lc] = (short)x;
          }
      __syncthreads();
      u16* dst = (pass == 0) ? Hi : Lo;
#pragma unroll
      for (int j = 0; j < 8; ++j)
        *(short8*)&dst[rowb + 8 * j] = *(const short8*)&T[lane * 72 + 8 * j];
    }
  } else {
    // V: [B,H,D,S] layout, compact key columns; predicate j < nk (tail stays 0)
#pragma unroll
    for (int mt = 0; mt < 4; ++mt) {
      const int jb = mloc + wm * 64 + mt * 16 + g * 4;
#pragma unroll
      for (int nt = 0; nt < 4; ++nt) {
        const int nE = nloc + wn * 64 + nt * 16 + lc;
        const int h = nE >> 6, d = nE & 63;
        const size_t rb = (((size_t)(bb * H_ + h)) * D_ + d) * S_;
#pragma unroll
        for (int r = 0; r < 4; ++r) {
          if (jb + r < nkb) Vp[rb + jb + r] = f2bf(acc[mt][nt][r] + bs[nt]);
        }
      }
    }
  }
}

// ---------------------------------------------------------------------------
// Kernel 2: MFMA flash attention. v11: K/V staged via global_load_lds
// (linear [64][64] bf16, 16B-chunk XOR swizzle chunk^=(row&7), pre-swizzled
// source), m97 double-barrier shape. No staging regs, no ds_writes for K/V.
// LDS 33,792 B -> 4 blocks/CU.
// ---------------------------------------------------------------------------
__global__ __launch_bounds__(256, 4) void attn_mfma_kernel(
    const u16* __restrict__ QpHi, const u16* __restrict__ QpLo,
    const u16* __restrict__ KpHi, const u16* __restrict__ KpLo,
    const u16* __restrict__ Vp,
    const int* __restrict__ nkArr,
    u16* __restrict__ AOHi)
{
  __shared__ __align__(16) short sm[16896];  // 33,792 B
  short* Khi = sm;                           // [64][64] swizzled (8,192 B)
  short* Klo = sm + 4096;                    // [64][64] swizzled
  short* Vt  = sm + 8192;                    // [64][64] swizzled (d-major)
  short* Pb  = sm + 12288;                   // 4 waves x [16][72]

  const int t = threadIdx.x;
  const int w = t >> 6, lane = t & 63;
  const int g = lane >> 4, lc = lane & 15;
  const int bh = blockIdx.y;
  const int b = bh >> 4, hh = bh & 15;
  const int q0 = blockIdx.x * 64;
  const size_t hb = (size_t)bh * S_ * D_;
  const u16* QgH = QpHi + hb;
  const u16* QgL = QpLo + hb;
  const u16* KgH = KpHi + hb;
  const u16* KgL = KpLo + hb;
  const u16* Vg  = Vp + hb;
  short* Pw = Pb + w * 1152;

  const int nk = nkArr[b];
  const int kend = ((nk + 63) >> 6) << 6;    // tiles of 64 compacted keys

  // ---- Q A-frags direct from global (lane lc = q-row, k = 8g..8g+7) ----
  short8 qh[2], ql[2];
  {
    const size_t base = (size_t)(q0 + 16 * w + lc) * D_ + 8 * g;
    qh[0] = *(const short8*)&QgH[base];
    qh[1] = *(const short8*)&QgH[base + 32];
    ql[0] = *(const short8*)&QgL[base];
    ql[1] = *(const short8*)&QgL[base + 32];
  }

  // ones column in B (n=0): lanes with lc==0 hold bf16(1.0) for all k
  short8 ones8 = {0, 0, 0, 0, 0, 0, 0, 0};
  if (lc == 0) {
    const short o = (short)0x3F80;
    ones8 = (short8){o, o, o, o, o, o, o, o};
  }

  f32x4 O[4];
  f32x4 Ol = (f32x4){0.f, 0.f, 0.f, 0.f};
#pragma unroll
  for (int dt = 0; dt < 4; ++dt) O[dt] = (f32x4){0.f, 0.f, 0.f, 0.f};
  float mst[4] = {-INFINITY, -INFINITY, -INFINITY, -INFINITY};

  // gload geometry: thread stages physical chunks p_i = (i*4+w)*64+lane,
  // i=0,1 (512 chunks = 8 KB per buffer). row = (i*4+w)*8 + (lane>>3);
  // source logical chunk = (lane&7) ^ (lane>>3).
  const int lch = (lane & 7) ^ (lane >> 3);
  int grow[2];
#pragma unroll
  for (int i = 0; i < 2; ++i) grow[i] = (i * 4 + w) * 8 + (lane >> 3);

  for (int kt = 0; kt < kend; kt += 64) {
    __syncthreads();                         // previous tile fully consumed
#pragma unroll
    for (int i = 0; i < 2; ++i) {
      const int row = grow[i];
      const size_t ko = (size_t)(kt + row) * D_ + lch * 8;
      gload16(KgH + ko, (char*)Khi + (i * 4 + w) * 1024);
      gload16(KgL + ko, (char*)Klo + (i * 4 + w) * 1024);
      gload16(Vg + (size_t)row * S_ + kt + lch * 8,
              (char*)Vt + (i * 4 + w) * 1024);
    }
    __syncthreads();                         // vmcnt drain: tile arrived

    // ---- scores: S[16q x 64k] ----
    f32x4 sc[4];
#pragma unroll
    for (int kt16 = 0; kt16 < 4; ++kt16) {
      const int R = 16 * kt16 + lc;
      const int s = lc & 7;
      const int o0 = R * 64 + ((g ^ s)) * 8;
      const int o1 = R * 64 + (((g + 4) ^ s)) * 8;
      const short8 kh0 = *(const short8*)&Khi[o0];
      const short8 kh1 = *(const short8*)&Khi[o1];
      const short8 kl0 = *(const short8*)&Klo[o0];
      const short8 kl1 = *(const short8*)&Klo[o1];
      f32x4 a = {0.f, 0.f, 0.f, 0.f};
      a = __builtin_amdgcn_mfma_f32_16x16x32_bf16(qh[0], kh0, a, 0, 0, 0);
      a = __builtin_amdgcn_mfma_f32_16x16x32_bf16(qh[1], kh1, a, 0, 0, 0);
      a = __builtin_amdgcn_mfma_f32_16x16x32_bf16(qh[0], kl0, a, 0, 0, 0);
      a = __builtin_amdgcn_mfma_f32_16x16x32_bf16(qh[1], kl1, a, 0, 0, 0);
      a = __builtin_amdgcn_mfma_f32_16x16x32_bf16(ql[0], kh0, a, 0, 0, 0);
      a = __builtin_amdgcn_mfma_f32_16x16x32_bf16(ql[1], kh1, a, 0, 0, 0);
      sc[kt16] = a;
    }

    // ---- tail masking: compacted cols >= nk are padding (garbage K) ----
    if (kt + 64 > nk) {
#pragma unroll
      for (int kt16 = 0; kt16 < 4; ++kt16) {
        if (kt + 16 * kt16 + lc >= nk) {
          sc[kt16][0] = -1e20f; sc[kt16][1] = -1e20f;
          sc[kt16][2] = -1e20f; sc[kt16][3] = -1e20f;
        }
      }
    }

    // ---- online max + exp (max butterfly only; sum comes from MFMA) ----
    float al[4];
#pragma unroll
    for (int r = 0; r < 4; ++r) {
      float vv = fmaxf(fmaxf(sc[0][r], sc[1][r]), fmaxf(sc[2][r], sc[3][r]));
      vv = fmaxf(vv, __shfl_xor(vv, 1));
      vv = fmaxf(vv, __shfl_xor(vv, 2));
      vv = fmaxf(vv, __shfl_xor(vv, 4));
      vv = fmaxf(vv, __shfl_xor(vv, 8));
      const float mn = fmaxf(mst[r], vv);
      al[r] = __expf(mst[r] - mn);           // first tile: exp(-inf)=0
      mst[r] = mn;
    }
#pragma unroll
    for (int kt16 = 0; kt16 < 4; ++kt16) {
#pragma unroll
      for (int r = 0; r < 4; ++r)
        sc[kt16][r] = __expf(sc[kt16][r] - mst[r]);
    }
    const f32x4 alv = {al[0], al[1], al[2], al[3]};
    O[0] *= alv; O[1] *= alv; O[2] *= alv; O[3] *= alv;
    Ol *= alv;
    // P: C-layout regs -> bf16 LDS (A-layout source for PV)
#pragma unroll
    for (int kt16 = 0; kt16 < 4; ++kt16) {
#pragma unroll
      for (int r = 0; r < 4; ++r)
        Pw[(4 * g + r) * 72 + 16 * kt16 + lc] = (short)f2bf(sc[kt16][r]);
    }

    // ---- PV + denominator via ones ----
    short8 pa[2];
    pa[0] = *(const short8*)&Pw[lc * 72 + 8 * g];
    pa[1] = *(const short8*)&Pw[lc * 72 + 32 + 8 * g];
    Ol = __builtin_amdgcn_mfma_f32_16x16x32_bf16(pa[0], ones8, Ol, 0, 0, 0);
    Ol = __builtin_amdgcn_mfma_f32_16x16x32_bf16(pa[1], ones8, Ol, 0, 0, 0);
#pragma unroll
    for (int dt = 0; dt < 4; ++dt) {
      const int R = 16 * dt + lc;
      const int s = lc & 7;
      const short8 vb0 = *(const short8*)&Vt[R * 64 + ((g ^ s)) * 8];
      const short8 vb1 = *(const short8*)&Vt[R * 64 + (((g + 4) ^ s)) * 8];
      O[dt] = __builtin_amdgcn_mfma_f32_16x16x32_bf16(pa[0], vb0, O[dt], 0, 0, 0);
      O[dt] = __builtin_amdgcn_mfma_f32_16x16x32_bf16(pa[1], vb1, O[dt], 0, 0, 0);
    }
  }

  // ---- epilogue: broadcast denominator (col 0 on lanes lc==0), normalize ----
#pragma unroll
  for (int r = 0; r < 4; ++r) {
    const float lv = __shfl(Ol[r], lane & 48);
    const float lir = 1.0f / lv;
    const int qrow = q0 + 16 * w + 4 * g + r;
    const size_t rowb = (size_t)(b * S_ + qrow) * E_ + hh * 64;
#pragma unroll
    for (int dt = 0; dt < 4; ++dt)
      AOHi[rowb + dt * 16 + lc] = f2bf(O[dt][r] * lir);
  }
}

// ---------------------------------------------------------------------------
// Kernel 3: output projection (round-10 version, unchanged): both operands
// staged by global_load_lds width=16, XOR swizzle chunk^=(row>>1)&3.
// Tile 64x128 (grid 512 blocks), 4 waves, wave = 32x64. LDS 12,288 B.
// ---------------------------------------------------------------------------
__global__ __launch_bounds__(256) void gemm_out_kernel(
    const u16* __restrict__ AHi,
    const u16* __restrict__ WHi,
    const float* __restrict__ bias, float* __restrict__ out)
{
  __shared__ __align__(16) short smem[6144];   // A[64][32] + B[128][32]
  short* Ah = smem;           // 4096 B
  short* Bh = smem + 2048;    // 8192 B

  const int t = threadIdx.x;
  const int m0 = blockIdx.x * 64;
  const int n0 = blockIdx.y * 128;
  const int w = t >> 6, lane = t & 63;
  const int g = lane >> 4, lc = lane & 15;
  const int wm = w & 1, wn = w >> 1;

  f32x4 acc[2][4];
#pragma unroll
  for (int i = 0; i < 2; ++i)
#pragma unroll
    for (int j = 0; j < 4; ++j) acc[i][j] = (f32x4){0.f, 0.f, 0.f, 0.f};

  for (int k0 = 0; k0 < E_; k0 += 32) {
    // stage: A 1 gload/wave, B 2 gloads/wave (pre-swizzled sources)
    {
      const int cA = w * 64 + lane;              // 0..255
      const int rowA = cA >> 2;
      const int subA = (cA & 3) ^ ((rowA >> 1) & 3);
      gload16(AHi + (size_t)(m0 + rowA) * E_ + k0 + subA * 8,
              (char*)Ah + w * 1024);
#pragma unroll
      for (int i = 0; i < 2; ++i) {
        const int c = (w * 2 + i) * 64 + lane;   // 0..511
        const int row = c >> 2;
        const int sub = (c & 3) ^ ((row >> 1) & 3);
        gload16(WHi + (size_t)(n0 + row) * E_ + k0 + sub * 8,
                (char*)Bh + (w * 2 + i) * 1024);
      }
    }
    __syncthreads();                 // vmcnt drain: tiles arrived

    short8 ah[2], bh[4];
#pragma unroll
    for (int mt = 0; mt < 2; ++mt) {
      const int row = wm * 32 + mt * 16 + lc;
      ah[mt] = *(const short8*)&Ah[row * 32 + ((g ^ ((row >> 1) & 3)) * 8)];
    }
#pragma unroll
    for (int nt = 0; nt < 4; ++nt) {
      const int row = wn * 64 + nt * 16 + lc;
      bh[nt] = *(const short8*)&Bh[row * 32 + ((g ^ ((row >> 1) & 3)) * 8)];
    }
#pragma unroll
    for (int mt = 0; mt < 2; ++mt)
#pragma unroll
      for (int nt = 0; nt < 4; ++nt)
        acc[mt][nt] = __builtin_amdgcn_mfma_f32_16x16x32_bf16(ah[mt], bh[nt], acc[mt][nt], 0, 0, 0);
    __syncthreads();                 // frags read -> safe to overwrite
  }

  float bs[4];
#pragma unroll
  for (int nt = 0; nt < 4; ++nt) bs[nt] = bias[n0 + wn * 64 + nt * 16 + lc];
#pragma unroll
  for (int nt = 0; nt < 4; ++nt) {
    const int nc = n0 + wn * 64 + nt * 16 + lc;
#pragma unroll
    for (int mt = 0; mt < 2; ++mt) {
#pragma unroll
      for (int r = 0; r < 4; ++r) {
        const int mrow = m0 + wm * 32 + mt * 16 + g * 4 + r;
        out[(size_t)mrow * E_ + nc] = acc[mt][nt][r] + bs[nt];
      }
    }
  }
}

// ---------------------------------------------------------------------------
extern "C" void kernel_launch(void* const* d_in, const int* in_sizes, int n_in,
                              void* d_out, int out_size, void* d_ws, size_t ws_size,
                              hipStream_t stream) {
  const float* q    = (const float*)d_in[0];
  const float* k    = (const float*)d_in[1];
  const float* v    = (const float*)d_in[2];
  const int*   mask = (const int*)d_in[3];
  const float* Wqkv = (const float*)d_in[4];
  const float* bqkv = (const float*)d_in[5];
  const float* Wout = (const float*)d_in[6];
  const float* bout = (const float*)d_in[7];
  float* out = (float*)d_out;

  // Workspace layout (64 MB).
  char* wsb = (char*)d_ws;
  u16* WqkvHi = (u16*)(wsb + 0);          //  6 MB
  u16* WqkvLo = (u16*)(wsb + 6291456);    //  6 MB
  u16* WoutHi = (u16*)(wsb + 12582912);   //  2 MB
  // WoutLo region (2 MB at 14680064) is scratch: split writes it, then the
  // scan kernel reuses the space for opos/nk (stream-ordered, safe).
  int* Opos   = (int*)(wsb + 14680064);   // 16 KB (B*S ints)
  int* Nk     = (int*)(wsb + 14680064 + 16384);  // 8 B
  u16* WoutLo = (u16*)(wsb + 14680064);   // (written then overwritten, unused)
  u16* QpHi   = (u16*)(wsb + 16777216);   //  8 MB
  u16* QpLo   = (u16*)(wsb + 25165824);   //  8 MB
  u16* KpHi   = (u16*)(wsb + 33554432);   //  8 MB
  u16* KpLo   = (u16*)(wsb + 41943040);   //  8 MB
  u16* Vp     = (u16*)(wsb + 50331648);   //  8 MB
  u16* AOHi   = (u16*)(wsb + 58720256);   //  8 MB

  hipLaunchKernelGGL(split_f32_kernel, dim3(3072), dim3(256), 0, stream,
                     Wqkv, WqkvHi, WqkvLo, 786432);
  hipLaunchKernelGGL(split_f32_kernel, dim3(1024), dim3(256), 0, stream,
                     Wout, WoutHi, WoutLo, 262144);
  hipLaunchKernelGGL(mask_scan_kernel, dim3(B_), dim3(256), 0, stream,
                     mask, Opos, Nk);
  // zero V so padded tail columns (>= nk) contribute exact 0 in PV
  hipMemsetAsync(Vp, 0, 8388608, stream);
  hipLaunchKernelGGL(gemm_qkv_kernel, dim3(M_ / 128, 24), dim3(256), 0, stream,
                     q, k, v, WqkvHi, WqkvLo, bqkv, Opos, Nk,
                     QpHi, QpLo, KpHi, KpLo, Vp);
  hipLaunchKernelGGL(attn_mfma_kernel, dim3(S_ / 64, B_ * H_), dim3(256), 0, stream,
                     QpHi, QpLo, KpHi, KpLo, Vp, Nk, AOHi);
  hipLaunchKernelGGL(gemm_out_kernel, dim3(M_ / 64, E_ / 128), dim3(256), 0, stream,
                     AOHi, WoutHi, bout, out);
}

// Round 12
// 284.343 us; speedup vs baseline: 1.0833x; 1.0833x over previous
//
#include <hip/hip_runtime.h>
#include <stdint.h>

// Problem dims (fixed by the reference)
constexpr int B_ = 2, S_ = 2048, E_ = 1024, H_ = 16, D_ = 64;
constexpr int M_ = B_ * S_;              // 4096 rows

typedef unsigned short u16;
typedef __attribute__((ext_vector_type(8))) short short8;
typedef __attribute__((ext_vector_type(4))) float f32x4;

__device__ __forceinline__ u16 f2bf(float f) {
  uint32_t u = __float_as_uint(f);
  return (u16)((u + 0x7FFFu + ((u >> 16) & 1u)) >> 16);  // RNE
}
// truncation split: hi = trunc16(x), lo = trunc16(x - hi). hi+lo ~ x to 2^-17.
__device__ __forceinline__ void tsplit(float x, u16& hi, u16& lo) {
  const uint32_t u = __float_as_uint(x);
  hi = (u16)(u >> 16);
  const float hif = __uint_as_float(u & 0xFFFF0000u);
  lo = (u16)(__float_as_uint(x - hif) >> 16);
}

// async global->LDS, 16 B per lane; LDS dest = wave-uniform base + lane*16.
typedef const __attribute__((address_space(1))) unsigned int GU32;
typedef __attribute__((address_space(3))) unsigned int LU32;
__device__ __forceinline__ void gload16(const void* g, void* l) {
  __builtin_amdgcn_global_load_lds((GU32*)g, (LU32*)l, 16, 0, 0);
}

// ---------------------------------------------------------------------------
// Kernel 0: split fp32 -> (hi, lo) bf16 pair, elementwise (weights).
// ---------------------------------------------------------------------------
__global__ __launch_bounds__(256) void split_f32_kernel(
    const float* __restrict__ src, u16* __restrict__ hi, u16* __restrict__ lo, int n4)
{
  const int i = blockIdx.x * 256 + threadIdx.x;
  if (i >= n4) return;
  const float4 x = ((const float4*)src)[i];
  ushort4 h, l;
  tsplit(x.x, h.x, l.x); tsplit(x.y, h.y, l.y);
  tsplit(x.z, h.z, l.z); tsplit(x.w, h.w, l.w);
  ((ushort4*)hi)[i] = h;
  ((ushort4*)lo)[i] = l;
}

// ---------------------------------------------------------------------------
// Kernel 0b: per-batch scan of key mask -> opos (compact slot j -> orig row s)
// and nk[b] (# unmasked keys).
// ---------------------------------------------------------------------------
__global__ __launch_bounds__(256) void mask_scan_kernel(
    const int* __restrict__ mask, int* __restrict__ opos, int* __restrict__ nk)
{
  __shared__ int tmp[256];
  __shared__ int coff;
  const int b = blockIdx.x, t = threadIdx.x;
  for (int c = t; c < S_; c += 256) opos[b * S_ + c] = 0;  // safe default
  if (t == 0) coff = 0;
  __syncthreads();
  for (int c = 0; c < S_; c += 256) {
    const int m = (mask[b * S_ + c + t] != 0) ? 1 : 0;
    int x = m;
    tmp[t] = x;
    __syncthreads();
#pragma unroll
    for (int off = 1; off < 256; off <<= 1) {
      const int v = (t >= off) ? tmp[t - off] : 0;
      __syncthreads();
      x += v;
      tmp[t] = x;
      __syncthreads();
    }
    const int base = coff;
    if (m) opos[b * S_ + base + x - 1] = c + t;  // scatter: slot -> orig row
    __syncthreads();
    if (t == 255) coff = base + x;
    __syncthreads();
  }
  if (t == 0) nk[b] = coff;
}

// ---------------------------------------------------------------------------
// Kernel 1: QKV projection, split-bf16 MFMA + key compaction.
// v12 = round-10 staging (A reg-staged + tsplit, B via global_load_lds w=16,
// XOR swizzle) restructured as T3 minimum 2-phase: double-buffered tile,
// stage(buf p^1, t+1) BEFORE compute(buf p), ONE __syncthreads per step —
// its vmcnt(0) drains gloads that had a full MFMA phase of cover.
// + XCD-aware block swizzle (768 blocks -> 3 B-panels per XCD L2).
// Tile 128x128, 4 waves (2m x 2n), wave = 64x64 (acc[4][4]).
// LDS 73,728 B (2 x 36,864) -> 2 blocks/CU.
// ---------------------------------------------------------------------------
__global__ __launch_bounds__(256) void gemm_qkv_kernel(
    const float* __restrict__ q, const float* __restrict__ k, const float* __restrict__ v,
    const u16* __restrict__ WHi, const u16* __restrict__ WLo,
    const float* __restrict__ bias,
    const int* __restrict__ Opos, const int* __restrict__ NkArr,
    u16* __restrict__ QpHi, u16* __restrict__ QpLo,
    u16* __restrict__ KpHi, u16* __restrict__ KpLo,
    u16* __restrict__ Vp)
{
  // per buffer: Ah[128][40] (5120) + Al[128][40] (5120) + Bh[128][32] (4096)
  //             + Bl[128][32] (4096) = 18,432 shorts; x2 buffers.
  __shared__ __align__(16) short smem[36864];  // 73,728 B

  const int t = threadIdx.x;
  // XCD swizzle: 768 blocks, XCD i gets 96 consecutive wg -> 3 B-panels.
  const int pl = blockIdx.x + 32 * blockIdx.y;
  const int wg = (pl & 7) * 96 + (pl >> 3);
  const int m0 = (wg & 31) * 128;
  const int n0g = (wg >> 5) * 128;           // global col in [0, 3072)
  const int proj = n0g >> 10;
  const int nloc = n0g & (E_ - 1);
  const bool split = (proj < 2);
  const int bb = m0 >> 11, mloc = m0 & (S_ - 1);
  const int nkb = NkArr[bb];
  if (proj != 0 && mloc >= nkb) return;      // compacted K/V: nothing to do

  const float* A = (proj == 0) ? q : (proj == 1) ? k : v;

  const int w = t >> 6, lane = t & 63;
  const int g = lane >> 4, lc = lane & 15;
  const int wm = w & 1, wn = w >> 1;
  const int sra = t >> 1, sca = (t & 1) * 16; // A staging: 2 thr/row, 16 f32

  // A source row (gathered through opos for K/V)
  int arow;
  if (proj == 0) arow = m0 + sra;
  else arow = bb * S_ + (Opos[bb * S_ + mloc + sra] & (S_ - 1));
  const float* Ab = A + (size_t)arow * E_ + sca;

  f32x4 acc[4][4];
#pragma unroll
  for (int i = 0; i < 4; ++i)
#pragma unroll
    for (int j = 0; j < 4; ++j) acc[i][j] = (f32x4){0.f, 0.f, 0.f, 0.f};

  auto loadA = [&](float4* a, int kk) {
#pragma unroll
    for (int i = 0; i < 4; ++i) a[i] = *(const float4*)(Ab + kk + 4 * i);
  };
  auto writeA = [&](const float4* a, short* Ah, short* Al) {
    ushort hh[16], ll[16];
#pragma unroll
    for (int i = 0; i < 4; ++i) {
      tsplit(a[i].x, hh[4 * i + 0], ll[4 * i + 0]);
      tsplit(a[i].y, hh[4 * i + 1], ll[4 * i + 1]);
      tsplit(a[i].z, hh[4 * i + 2], ll[4 * i + 2]);
      tsplit(a[i].w, hh[4 * i + 3], ll[4 * i + 3]);
    }
    *(short8*)&Ah[sra * 40 + sca]     = *(const short8*)&hh[0];
    *(short8*)&Ah[sra * 40 + sca + 8] = *(const short8*)&hh[8];
    if (split) {
      *(short8*)&Al[sra * 40 + sca]     = *(const short8*)&ll[0];
      *(short8*)&Al[sra * 40 + sca + 8] = *(const short8*)&ll[8];
    }
  };
  // B: 512 chunks of 16B per tile; wave w stages chunks [(w*2+i)*64 + lane].
  // Physical chunk p holds logical chunk (p&3)^((row>>1)&3) of row p>>2.
  auto gloadB = [&](int k0, short* Bh, short* Bl) {
#pragma unroll
    for (int i = 0; i < 2; ++i) {
      const int c = (w * 2 + i) * 64 + lane;
      const int row = c >> 2;
      const int sub = (c & 3) ^ ((row >> 1) & 3);
      const size_t go = (size_t)(n0g + row) * E_ + k0 + sub * 8;
      gload16(WHi + go, (char*)Bh + (w * 2 + i) * 1024);
      if (split) gload16(WLo + go, (char*)Bl + (w * 2 + i) * 1024);
    }
  };

  // prologue: stage tile 0 into buf0; prefetch A regs for tile 1
  float4 ar[4];
  loadA(ar, 0);
  writeA(ar, smem, smem + 5120);
  gloadB(0, smem + 10240, smem + 14336);
  loadA(ar, 32);
  __syncthreads();                 // buf0 ready (vmcnt + lgkm drained)

  for (int k0 = 0; k0 < E_; k0 += 32) {
    const int p = (k0 >> 5) & 1;
    short* cb = smem + p * 18432;        // current buffer
    short* nb = smem + (p ^ 1) * 18432;  // next buffer
    // stage t+1 into nb (gloads stay in flight across the whole compute)
    if (k0 + 32 < E_) {
      writeA(ar, nb, nb + 5120);
      gloadB(k0 + 32, nb + 10240, nb + 14336);
    }
    if (k0 + 64 < E_) loadA(ar, k0 + 64);

    short8 ah[4], al[4], bh[4], bl[4];
#pragma unroll
    for (int mt = 0; mt < 4; ++mt) {
      const int ro = (wm * 64 + mt * 16 + lc) * 40 + g * 8;
      ah[mt] = *(const short8*)&cb[ro];
      if (split) al[mt] = *(const short8*)&cb[5120 + ro];
    }
#pragma unroll
    for (int nt = 0; nt < 4; ++nt) {
      const int row = wn * 64 + nt * 16 + lc;
      const int ro = row * 32 + ((g ^ ((row >> 1) & 3)) * 8);
      bh[nt] = *(const short8*)&cb[10240 + ro];
      if (split) bl[nt] = *(const short8*)&cb[14336 + ro];
    }
#pragma unroll
    for (int mt = 0; mt < 4; ++mt)
#pragma unroll
      for (int nt = 0; nt < 4; ++nt) {
        f32x4 a = acc[mt][nt];
        a = __builtin_amdgcn_mfma_f32_16x16x32_bf16(ah[mt], bh[nt], a, 0, 0, 0);
        if (split) {
          a = __builtin_amdgcn_mfma_f32_16x16x32_bf16(ah[mt], bl[nt], a, 0, 0, 0);
          a = __builtin_amdgcn_mfma_f32_16x16x32_bf16(al[mt], bh[nt], a, 0, 0, 0);
        }
        acc[mt][nt] = a;
      }
    __syncthreads();   // drains nb gloads (full phase of cover) + lgkm;
                       // all waves done reading cb -> next iter may overwrite
  }

  // ---- epilogue ----
  float bs[4];
#pragma unroll
  for (int nt = 0; nt < 4; ++nt) bs[nt] = bias[n0g + wn * 64 + nt * 16 + lc];

  if (proj < 2) {
    // each wave's 64 n-cols = exactly one head
    u16* Hi = (proj == 0) ? QpHi : KpHi;
    u16* Lo = (proj == 0) ? QpLo : KpLo;
    const int hwave = (nloc + wn * 64) >> 6;
    short* T = smem + w * 4608;               // per-wave [64][72] u16
    const int srow_out = (proj == 0) ? ((m0 + wm * 64 + lane) & (S_ - 1))
                                     : (mloc + wm * 64 + lane);
    const size_t rowb = (((size_t)(bb * H_ + hwave)) * S_ + srow_out) * D_;
#pragma unroll
    for (int pass = 0; pass < 2; ++pass) {
      __syncthreads();                        // LDS free / prev pass reads done
#pragma unroll
      for (int nt = 0; nt < 4; ++nt)
#pragma unroll
        for (int mt = 0; mt < 4; ++mt)
#pragma unroll
          for (int r = 0; r < 4; ++r) {
            const float val = acc[mt][nt][r] + bs[nt];
            const uint32_t u = __float_as_uint(val);
            u16 x;
            if (pass == 0) x = (u16)(u >> 16);
            else {
              const float hif = __uint_as_float(u & 0xFFFF0000u);
              x = (u16)(__float_as_uint(val - hif) >> 16);
            }
            T[(mt * 16 + g * 4 + r) * 72 + nt * 16 + lc] = (short)x;
          }
      __syncthreads();
      u16* dst = (pass == 0) ? Hi : Lo;
#pragma unroll
      for (int j = 0; j < 8; ++j)
        *(short8*)&dst[rowb + 8 * j] = *(const short8*)&T[lane * 72 + 8 * j];
    }
  } else {
    // V: [B,H,D,S] layout, compact key columns; predicate j < nk (tail stays 0)
#pragma unroll
    for (int mt = 0; mt < 4; ++mt) {
      const int jb = mloc + wm * 64 + mt * 16 + g * 4;
#pragma unroll
      for (int nt = 0; nt < 4; ++nt) {
        const int nE = nloc + wn * 64 + nt * 16 + lc;
        const int h = nE >> 6, d = nE & 63;
        const size_t rb = (((size_t)(bb * H_ + h)) * D_ + d) * S_;
#pragma unroll
        for (int r = 0; r < 4; ++r) {
          if (jb + r < nkb) Vp[rb + jb + r] = f2bf(acc[mt][nt][r] + bs[nt]);
        }
      }
    }
  }
}

// ---------------------------------------------------------------------------
// Kernel 2: MFMA flash attention. v12 = round-11 gload version (neutral,
// fewer regs) + XCD-aware block swizzle (1024 blocks -> 4 K/V sets per XCD).
// LDS 33,792 B -> 4 blocks/CU.
// ---------------------------------------------------------------------------
__global__ __launch_bounds__(256, 4) void attn_mfma_kernel(
    const u16* __restrict__ QpHi, const u16* __restrict__ QpLo,
    const u16* __restrict__ KpHi, const u16* __restrict__ KpLo,
    const u16* __restrict__ Vp,
    const int* __restrict__ nkArr,
    u16* __restrict__ AOHi)
{
  __shared__ __align__(16) short sm[16896];  // 33,792 B
  short* Khi = sm;                           // [64][64] swizzled (8,192 B)
  short* Klo = sm + 4096;                    // [64][64] swizzled
  short* Vt  = sm + 8192;                    // [64][64] swizzled (d-major)
  short* Pb  = sm + 12288;                   // 4 waves x [16][72]

  const int t = threadIdx.x;
  const int w = t >> 6, lane = t & 63;
  const int g = lane >> 4, lc = lane & 15;
  // XCD swizzle: 1024 blocks, XCD i gets 128 consecutive wg -> 4 (b,h) sets.
  const int pl = blockIdx.x + 32 * blockIdx.y;
  const int wgid = (pl & 7) * 128 + (pl >> 3);
  const int bh = wgid >> 5;
  const int q0 = (wgid & 31) * 64;
  const int b = bh >> 4, hh = bh & 15;
  const size_t hb = (size_t)bh * S_ * D_;
  const u16* QgH = QpHi + hb;
  const u16* QgL = QpLo + hb;
  const u16* KgH = KpHi + hb;
  const u16* KgL = KpLo + hb;
  const u16* Vg  = Vp + hb;
  short* Pw = Pb + w * 1152;

  const int nk = nkArr[b];
  const int kend = ((nk + 63) >> 6) << 6;    // tiles of 64 compacted keys

  // ---- Q A-frags direct from global (lane lc = q-row, k = 8g..8g+7) ----
  short8 qh[2], ql[2];
  {
    const size_t base = (size_t)(q0 + 16 * w + lc) * D_ + 8 * g;
    qh[0] = *(const short8*)&QgH[base];
    qh[1] = *(const short8*)&QgH[base + 32];
    ql[0] = *(const short8*)&QgL[base];
    ql[1] = *(const short8*)&QgL[base + 32];
  }

  // ones column in B (n=0): lanes with lc==0 hold bf16(1.0) for all k
  short8 ones8 = {0, 0, 0, 0, 0, 0, 0, 0};
  if (lc == 0) {
    const short o = (short)0x3F80;
    ones8 = (short8){o, o, o, o, o, o, o, o};
  }

  f32x4 O[4];
  f32x4 Ol = (f32x4){0.f, 0.f, 0.f, 0.f};
#pragma unroll
  for (int dt = 0; dt < 4; ++dt) O[dt] = (f32x4){0.f, 0.f, 0.f, 0.f};
  float mst[4] = {-INFINITY, -INFINITY, -INFINITY, -INFINITY};

  // gload geometry: thread stages physical chunks p_i = (i*4+w)*64+lane,
  // i=0,1. row = (i*4+w)*8 + (lane>>3); source logical chunk = (lane&7)^(lane>>3).
  const int lch = (lane & 7) ^ (lane >> 3);
  int grow[2];
#pragma unroll
  for (int i = 0; i < 2; ++i) grow[i] = (i * 4 + w) * 8 + (lane >> 3);

  for (int kt = 0; kt < kend; kt += 64) {
    __syncthreads();                         // previous tile fully consumed
#pragma unroll
    for (int i = 0; i < 2; ++i) {
      const int row = grow[i];
      const size_t ko = (size_t)(kt + row) * D_ + lch * 8;
      gload16(KgH + ko, (char*)Khi + (i * 4 + w) * 1024);
      gload16(KgL + ko, (char*)Klo + (i * 4 + w) * 1024);
      gload16(Vg + (size_t)row * S_ + kt + lch * 8,
              (char*)Vt + (i * 4 + w) * 1024);
    }
    __syncthreads();                         // vmcnt drain: tile arrived

    // ---- scores: S[16q x 64k] ----
    f32x4 sc[4];
#pragma unroll
    for (int kt16 = 0; kt16 < 4; ++kt16) {
      const int R = 16 * kt16 + lc;
      const int s = lc & 7;
      const int o0 = R * 64 + ((g ^ s)) * 8;
      const int o1 = R * 64 + (((g + 4) ^ s)) * 8;
      const short8 kh0 = *(const short8*)&Khi[o0];
      const short8 kh1 = *(const short8*)&Khi[o1];
      const short8 kl0 = *(const short8*)&Klo[o0];
      const short8 kl1 = *(const short8*)&Klo[o1];
      f32x4 a = {0.f, 0.f, 0.f, 0.f};
      a = __builtin_amdgcn_mfma_f32_16x16x32_bf16(qh[0], kh0, a, 0, 0, 0);
      a = __builtin_amdgcn_mfma_f32_16x16x32_bf16(qh[1], kh1, a, 0, 0, 0);
      a = __builtin_amdgcn_mfma_f32_16x16x32_bf16(qh[0], kl0, a, 0, 0, 0);
      a = __builtin_amdgcn_mfma_f32_16x16x32_bf16(qh[1], kl1, a, 0, 0, 0);
      a = __builtin_amdgcn_mfma_f32_16x16x32_bf16(ql[0], kh0, a, 0, 0, 0);
      a = __builtin_amdgcn_mfma_f32_16x16x32_bf16(ql[1], kh1, a, 0, 0, 0);
      sc[kt16] = a;
    }

    // ---- tail masking: compacted cols >= nk are padding (garbage K) ----
    if (kt + 64 > nk) {
#pragma unroll
      for (int kt16 = 0; kt16 < 4; ++kt16) {
        if (kt + 16 * kt16 + lc >= nk) {
          sc[kt16][0] = -1e20f; sc[kt16][1] = -1e20f;
          sc[kt16][2] = -1e20f; sc[kt16][3] = -1e20f;
        }
      }
    }

    // ---- online max + exp (max butterfly only; sum comes from MFMA) ----
    float al[4];
#pragma unroll
    for (int r = 0; r < 4; ++r) {
      float vv = fmaxf(fmaxf(sc[0][r], sc[1][r]), fmaxf(sc[2][r], sc[3][r]));
      vv = fmaxf(vv, __shfl_xor(vv, 1));
      vv = fmaxf(vv, __shfl_xor(vv, 2));
      vv = fmaxf(vv, __shfl_xor(vv, 4));
      vv = fmaxf(vv, __shfl_xor(vv, 8));
      const float mn = fmaxf(mst[r], vv);
      al[r] = __expf(mst[r] - mn);           // first tile: exp(-inf)=0
      mst[r] = mn;
    }
#pragma unroll
    for (int kt16 = 0; kt16 < 4; ++kt16) {
#pragma unroll
      for (int r = 0; r < 4; ++r)
        sc[kt16][r] = __expf(sc[kt16][r] - mst[r]);
    }
    const f32x4 alv = {al[0], al[1], al[2], al[3]};
    O[0] *= alv; O[1] *= alv; O[2] *= alv; O[3] *= alv;
    Ol *= alv;
    // P: C-layout regs -> bf16 LDS (A-layout source for PV)
#pragma unroll
    for (int kt16 = 0; kt16 < 4; ++kt16) {
#pragma unroll
      for (int r = 0; r < 4; ++r)
        Pw[(4 * g + r) * 72 + 16 * kt16 + lc] = (short)f2bf(sc[kt16][r]);
    }

    // ---- PV + denominator via ones ----
    short8 pa[2];
    pa[0] = *(const short8*)&Pw[lc * 72 + 8 * g];
    pa[1] = *(const short8*)&Pw[lc * 72 + 32 + 8 * g];
    Ol = __builtin_amdgcn_mfma_f32_16x16x32_bf16(pa[0], ones8, Ol, 0, 0, 0);
    Ol = __builtin_amdgcn_mfma_f32_16x16x32_bf16(pa[1], ones8, Ol, 0, 0, 0);
#pragma unroll
    for (int dt = 0; dt < 4; ++dt) {
      const int R = 16 * dt + lc;
      const int s = lc & 7;
      const short8 vb0 = *(const short8*)&Vt[R * 64 + ((g ^ s)) * 8];
      const short8 vb1 = *(const short8*)&Vt[R * 64 + (((g + 4) ^ s)) * 8];
      O[dt] = __builtin_amdgcn_mfma_f32_16x16x32_bf16(pa[0], vb0, O[dt], 0, 0, 0);
      O[dt] = __builtin_amdgcn_mfma_f32_16x16x32_bf16(pa[1], vb1, O[dt], 0, 0, 0);
    }
  }

  // ---- epilogue: broadcast denominator (col 0 on lanes lc==0), normalize ----
#pragma unroll
  for (int r = 0; r < 4; ++r) {
    const float lv = __shfl(Ol[r], lane & 48);
    const float lir = 1.0f / lv;
    const int qrow = q0 + 16 * w + 4 * g + r;
    const size_t rowb = (size_t)(b * S_ + qrow) * E_ + hh * 64;
#pragma unroll
    for (int dt = 0; dt < 4; ++dt)
      AOHi[rowb + dt * 16 + lc] = f2bf(O[dt][r] * lir);
  }
}

// ---------------------------------------------------------------------------
// Kernel 3: output projection (round-10 version + XCD swizzle): both operands
// staged by global_load_lds width=16, XOR swizzle chunk^=(row>>1)&3.
// Tile 64x128 (grid 512 blocks -> 1 B-panel per XCD), 4 waves, wave = 32x64.
// LDS 12,288 B.
// ---------------------------------------------------------------------------
__global__ __launch_bounds__(256) void gemm_out_kernel(
    const u16* __restrict__ AHi,
    const u16* __restrict__ WHi,
    const float* __restrict__ bias, float* __restrict__ out)
{
  __shared__ __align__(16) short smem[6144];   // A[64][32] + B[128][32]
  short* Ah = smem;           // 4096 B
  short* Bh = smem + 2048;    // 8192 B

  const int t = threadIdx.x;
  // XCD swizzle: 512 blocks, XCD i gets 64 consecutive wg -> 1 B-panel.
  const int pl = blockIdx.x + 64 * blockIdx.y;
  const int wg = (pl & 7) * 64 + (pl >> 3);
  const int m0 = (wg & 63) * 64;
  const int n0 = (wg >> 6) * 128;
  const int w = t >> 6, lane = t & 63;
  const int g = lane >> 4, lc = lane & 15;
  const int wm = w & 1, wn = w >> 1;

  f32x4 acc[2][4];
#pragma unroll
  for (int i = 0; i < 2; ++i)
#pragma unroll
    for (int j = 0; j < 4; ++j) acc[i][j] = (f32x4){0.f, 0.f, 0.f, 0.f};

  for (int k0 = 0; k0 < E_; k0 += 32) {
    // stage: A 1 gload/wave, B 2 gloads/wave (pre-swizzled sources)
    {
      const int cA = w * 64 + lane;              // 0..255
      const int rowA = cA >> 2;
      const int subA = (cA & 3) ^ ((rowA >> 1) & 3);
      gload16(AHi + (size_t)(m0 + rowA) * E_ + k0 + subA * 8,
              (char*)Ah + w * 1024);
#pragma unroll
      for (int i = 0; i < 2; ++i) {
        const int c = (w * 2 + i) * 64 + lane;   // 0..511
        const int row = c >> 2;
        const int sub = (c & 3) ^ ((row >> 1) & 3);
        gload16(WHi + (size_t)(n0 + row) * E_ + k0 + sub * 8,
                (char*)Bh + (w * 2 + i) * 1024);
      }
    }
    __syncthreads();                 // vmcnt drain: tiles arrived

    short8 ah[2], bh[4];
#pragma unroll
    for (int mt = 0; mt < 2; ++mt) {
      const int row = wm * 32 + mt * 16 + lc;
      ah[mt] = *(const short8*)&Ah[row * 32 + ((g ^ ((row >> 1) & 3)) * 8)];
    }
#pragma unroll
    for (int nt = 0; nt < 4; ++nt) {
      const int row = wn * 64 + nt * 16 + lc;
      bh[nt] = *(const short8*)&Bh[row * 32 + ((g ^ ((row >> 1) & 3)) * 8)];
    }
#pragma unroll
    for (int mt = 0; mt < 2; ++mt)
#pragma unroll
      for (int nt = 0; nt < 4; ++nt)
        acc[mt][nt] = __builtin_amdgcn_mfma_f32_16x16x32_bf16(ah[mt], bh[nt], acc[mt][nt], 0, 0, 0);
    __syncthreads();                 // frags read -> safe to overwrite
  }

  float bs[4];
#pragma unroll
  for (int nt = 0; nt < 4; ++nt) bs[nt] = bias[n0 + wn * 64 + nt * 16 + lc];
#pragma unroll
  for (int nt = 0; nt < 4; ++nt) {
    const int nc = n0 + wn * 64 + nt * 16 + lc;
#pragma unroll
    for (int mt = 0; mt < 2; ++mt) {
#pragma unroll
      for (int r = 0; r < 4; ++r) {
        const int mrow = m0 + wm * 32 + mt * 16 + g * 4 + r;
        out[(size_t)mrow * E_ + nc] = acc[mt][nt][r] + bs[nt];
      }
    }
  }
}

// ---------------------------------------------------------------------------
extern "C" void kernel_launch(void* const* d_in, const int* in_sizes, int n_in,
                              void* d_out, int out_size, void* d_ws, size_t ws_size,
                              hipStream_t stream) {
  const float* q    = (const float*)d_in[0];
  const float* k    = (const float*)d_in[1];
  const float* v    = (const float*)d_in[2];
  const int*   mask = (const int*)d_in[3];
  const float* Wqkv = (const float*)d_in[4];
  const float* bqkv = (const float*)d_in[5];
  const float* Wout = (const float*)d_in[6];
  const float* bout = (const float*)d_in[7];
  float* out = (float*)d_out;

  // Workspace layout (64 MB).
  char* wsb = (char*)d_ws;
  u16* WqkvHi = (u16*)(wsb + 0);          //  6 MB
  u16* WqkvLo = (u16*)(wsb + 6291456);    //  6 MB
  u16* WoutHi = (u16*)(wsb + 12582912);   //  2 MB
  // WoutLo region (2 MB at 14680064) is scratch: split writes it, then the
  // scan kernel reuses the space for opos/nk (stream-ordered, safe).
  int* Opos   = (int*)(wsb + 14680064);   // 16 KB (B*S ints)
  int* Nk     = (int*)(wsb + 14680064 + 16384);  // 8 B
  u16* WoutLo = (u16*)(wsb + 14680064);   // (written then overwritten, unused)
  u16* QpHi   = (u16*)(wsb + 16777216);   //  8 MB
  u16* QpLo   = (u16*)(wsb + 25165824);   //  8 MB
  u16* KpHi   = (u16*)(wsb + 33554432);   //  8 MB
  u16* KpLo   = (u16*)(wsb + 41943040);   //  8 MB
  u16* Vp     = (u16*)(wsb + 50331648);   //  8 MB
  u16* AOHi   = (u16*)(wsb + 58720256);   //  8 MB

  hipLaunchKernelGGL(split_f32_kernel, dim3(3072), dim3(256), 0, stream,
                     Wqkv, WqkvHi, WqkvLo, 786432);
  hipLaunchKernelGGL(split_f32_kernel, dim3(1024), dim3(256), 0, stream,
                     Wout, WoutHi, WoutLo, 262144);
  hipLaunchKernelGGL(mask_scan_kernel, dim3(B_), dim3(256), 0, stream,
                     mask, Opos, Nk);
  // zero V so padded tail columns (>= nk) contribute exact 0 in PV
  hipMemsetAsync(Vp, 0, 8388608, stream);
  hipLaunchKernelGGL(gemm_qkv_kernel, dim3(M_ / 128, 24), dim3(256), 0, stream,
                     q, k, v, WqkvHi, WqkvLo, bqkv, Opos, Nk,
                     QpHi, QpLo, KpHi, KpLo, Vp);
  hipLaunchKernelGGL(attn_mfma_kernel, dim3(S_ / 64, B_ * H_), dim3(256), 0, stream,
                     QpHi, QpLo, KpHi, KpLo, Vp, Nk, AOHi);
  hipLaunchKernelGGL(gemm_out_kernel, dim3(M_ / 64, E_ / 128), dim3(256), 0, stream,
                     AOHi, WoutHi, bout, out);
}